// Round 18
// baseline (264.871 us; speedup 1.0000x reference)
//
#include <hip/hip_runtime.h>
#include <hip/hip_bf16.h>
#include <stdint.h>

#define DM   2048
#define SEQ  2048
#define NB   2
#define NH   16
#define DK   128
#define MTOT (NB * SEQ) // 4096
#define NT2  (SEQ / 32) // 64 k-tiles of 32

typedef __bf16 bf16;
typedef __bf16 bf16x8 __attribute__((ext_vector_type(8)));
typedef __bf16 bf16x4v __attribute__((ext_vector_type(4)));
typedef float f32x4 __attribute__((ext_vector_type(4)));
typedef float f32x16 __attribute__((ext_vector_type(16)));
typedef unsigned uint2v __attribute__((ext_vector_type(2)));

__device__ __forceinline__ void gload_lds16(const void* g, void* l) {
  __builtin_amdgcn_global_load_lds((__attribute__((address_space(1))) void*)(g),
                                   (__attribute__((address_space(3))) void*)(l),
                                   16, 0, 0);
}

__device__ __forceinline__ f32x4 mfma16(bf16x8 a, bf16x8 b, f32x4 c) {
  return __builtin_amdgcn_mfma_f32_16x16x32_bf16(a, b, c, 0, 0, 0);
}
__device__ __forceinline__ f32x16 mfma32(bf16x8 a, bf16x8 b, f32x16 c) {
  return __builtin_amdgcn_mfma_f32_32x32x16_bf16(a, b, c, 0, 0, 0);
}
__device__ __forceinline__ uint32_t cvtpk(float lo, float hi) {
  uint32_t r;
  asm("v_cvt_pk_bf16_f32 %0, %1, %2" : "=v"(r) : "v"(lo), "v"(hi));
  return r;
}
__device__ __forceinline__ float exp2_fast(float x) {
  float r;
  asm("v_exp_f32 %0, %1" : "=v"(r) : "v"(x));
  return r;
}

// ---------------- fused fp32 -> bf16 cast: states + 4 weights, one launch ----------------
__global__ void cast_all_kernel(const float* __restrict__ s,
                                const float* __restrict__ w0, const float* __restrict__ w1,
                                const float* __restrict__ w2, const float* __restrict__ w3,
                                bf16* __restrict__ sb, bf16* __restrict__ wb) {
  const int i = blockIdx.x * blockDim.x + threadIdx.x;
  const int nAct4 = MTOT * DM / 4;
  const int nW4 = DM * DM / 4;
  const float* src;
  bf16* dst;
  int idx;
  if (i < nAct4) {
    src = s; dst = sb; idx = i;
  } else {
    const int j = i - nAct4;
    const int seg = j >> 20;                 // nW4 == 2^20
    src = (seg == 0) ? w0 : (seg == 1) ? w1 : (seg == 2) ? w2 : w3;
    dst = wb + ((size_t)seg << 20) * 4;
    idx = j & (nW4 - 1);
  }
  float4 v = reinterpret_cast<const float4*>(src)[idx];
  bf16x4v o;
  o[0] = (bf16)v.x; o[1] = (bf16)v.y; o[2] = (bf16)v.z; o[3] = (bf16)v.w;
  *reinterpret_cast<bf16x4v*>(dst + (size_t)idx * 4) = o;
}

// ---------------- merged QKV GEMM (128x128 tile, 4 waves — proven 2-D grid) ----------------
// Q output is pre-scaled by key_scale*log2(e) so attn's logit math is a single FMA.
__global__ __launch_bounds__(256, 2) void qkv_gemm(
    const bf16* __restrict__ A, const bf16* __restrict__ Wcat,
    const float* __restrict__ qb, const float* __restrict__ kb, const float* __restrict__ vb,
    bf16* __restrict__ qo, bf16* __restrict__ ko, bf16* __restrict__ vo) {
  __shared__ bf16 lA[128 * 64];
  __shared__ bf16 lB[128 * 64];

  const int tid = threadIdx.x;
  const int lane = tid & 63;
  const int wid = tid >> 6;
  const int wr = wid >> 1, wc = wid & 1;
  const int row0 = blockIdx.y * 128;
  const int col0 = blockIdx.x * 128;
  const int third = col0 >> 11;              // 0=q, 1=k, 2=v
  const float* bias = (third == 0) ? qb : (third == 1) ? kb : vb;
  const float osc = (third == 0) ? 0.12751740f : 1.0f;  // key_scale * log2(e) folded into Q

  const int srow = lane >> 3;
  const int scol = ((lane & 7) ^ srow) * 8;

  const int fr = lane & 15;
  const int fg = lane >> 4;

  f32x4 acc[4][4];
#pragma unroll
  for (int m = 0; m < 4; ++m)
#pragma unroll
    for (int n = 0; n < 4; ++n) { f32x4 z = {0.f, 0.f, 0.f, 0.f}; acc[m][n] = z; }

  for (int kt = 0; kt < DM / 64; ++kt) {
    const int k0 = kt * 64;
    __syncthreads();
#pragma unroll
    for (int i = 0; i < 4; ++i) {
      const int chunk = wid * 4 + i;
      const int r = chunk * 8 + srow;
      gload_lds16(A + (size_t)(row0 + r) * DM + k0 + scol, lA + chunk * 512);
      gload_lds16(Wcat + (size_t)(col0 + r) * DM + k0 + scol, lB + chunk * 512);
    }
    __syncthreads();
#pragma unroll
    for (int kk = 0; kk < 2; ++kk) {
      bf16x8 af[4], bw[4];
#pragma unroll
      for (int m = 0; m < 4; ++m) {
        const int r = wr * 64 + m * 16 + fr;
        const int cb = (kk * 64 + fg * 16) ^ ((r & 7) << 4);
        af[m] = *(const bf16x8*)((const char*)lA + r * 128 + cb);
      }
#pragma unroll
      for (int n = 0; n < 4; ++n) {
        const int r = wc * 64 + n * 16 + fr;
        const int cb = (kk * 64 + fg * 16) ^ ((r & 7) << 4);
        bw[n] = *(const bf16x8*)((const char*)lB + r * 128 + cb);
      }
#pragma unroll
      for (int m = 0; m < 4; ++m)
#pragma unroll
        for (int n = 0; n < 4; ++n) acc[m][n] = mfma16(af[m], bw[n], acc[m][n]);
    }
  }

#pragma unroll
  for (int m = 0; m < 4; ++m) {
#pragma unroll
    for (int n = 0; n < 4; ++n) {
      const int colg = col0 + wc * 64 + n * 16 + fr;
      const int col = colg & 2047;           // within third
      const float bs = bias[col];
      const int rbase = row0 + wr * 64 + m * 16 + fg * 4;
      const int h = col >> 7, d = col & 127;
      if (third < 2) {
        bf16* o = (third == 0) ? qo : ko;
#pragma unroll
        for (int r = 0; r < 4; ++r) {
          const int row = rbase + r;
          const int b = row >> 11, s = row & 2047;
          o[(((size_t)(b * NH + h) * SEQ + s) << 7) + d] = (bf16)((acc[m][n][r] + bs) * osc);
        }
      } else {
        const int b = rbase >> 11, s = rbase & 2047;
        bf16x4v pk;
#pragma unroll
        for (int r = 0; r < 4; ++r) pk[r] = (bf16)(acc[m][n][r] + bs);
        *reinterpret_cast<bf16x4v*>(vo + ((size_t)((b * NH + h) * DK + d) * SEQ + s)) = pk;
      }
    }
  }
}

// ---------------- O-projection GEMM (128x128, f32 out — proven 2-D grid) ----------------
__global__ __launch_bounds__(256, 2) void gemm_oproj(
    const bf16* __restrict__ A, const bf16* __restrict__ W,
    const float* __restrict__ bias, float* __restrict__ out) {
  __shared__ bf16 lA[128 * 64];
  __shared__ bf16 lB[128 * 64];

  const int tid = threadIdx.x;
  const int lane = tid & 63;
  const int wid = tid >> 6;
  const int wr = wid >> 1, wc = wid & 1;
  const int row0 = blockIdx.y * 128;
  const int col0 = blockIdx.x * 128;

  const int srow = lane >> 3;
  const int scol = ((lane & 7) ^ srow) * 8;

  const int fr = lane & 15;
  const int fg = lane >> 4;

  f32x4 acc[4][4];
#pragma unroll
  for (int m = 0; m < 4; ++m)
#pragma unroll
    for (int n = 0; n < 4; ++n) { f32x4 z = {0.f, 0.f, 0.f, 0.f}; acc[m][n] = z; }

  for (int kt = 0; kt < DM / 64; ++kt) {
    const int k0 = kt * 64;
    __syncthreads();
#pragma unroll
    for (int i = 0; i < 4; ++i) {
      const int chunk = wid * 4 + i;
      const int r = chunk * 8 + srow;
      gload_lds16(A + (size_t)(row0 + r) * DM + k0 + scol, lA + chunk * 512);
      gload_lds16(W + (size_t)(col0 + r) * DM + k0 + scol, lB + chunk * 512);
    }
    __syncthreads();
#pragma unroll
    for (int kk = 0; kk < 2; ++kk) {
      bf16x8 af[4], bw[4];
#pragma unroll
      for (int m = 0; m < 4; ++m) {
        const int r = wr * 64 + m * 16 + fr;
        const int cb = (kk * 64 + fg * 16) ^ ((r & 7) << 4);
        af[m] = *(const bf16x8*)((const char*)lA + r * 128 + cb);
      }
#pragma unroll
      for (int n = 0; n < 4; ++n) {
        const int r = wc * 64 + n * 16 + fr;
        const int cb = (kk * 64 + fg * 16) ^ ((r & 7) << 4);
        bw[n] = *(const bf16x8*)((const char*)lB + r * 128 + cb);
      }
#pragma unroll
      for (int m = 0; m < 4; ++m)
#pragma unroll
        for (int n = 0; n < 4; ++n) acc[m][n] = mfma16(af[m], bw[n], acc[m][n]);
    }
  }

#pragma unroll
  for (int m = 0; m < 4; ++m) {
#pragma unroll
    for (int n = 0; n < 4; ++n) {
      const int col = col0 + wc * 64 + n * 16 + fr;
      const float bs = bias[col];
      const int rbase = row0 + wr * 64 + m * 16 + fg * 4;
#pragma unroll
      for (int r = 0; r < 4; ++r) {
        const int row = rbase + r;
        out[(size_t)row * DM + col] = acc[m][n][r] + bs;
      }
    }
  }
}

// ---------------- flash attention: KVBLK=32, 5 blocks/CU (32 KB LDS) ----------------
// Proven per-wave math (swapped QK^T, fixed-ref softmax, permlane pack) on half-size
// k-tiles: p[1], lg[16], mk[4]; K tile [32][256B] swizzled; V as 32 quad-d virtual
// 256B rows (vp=d>>2, slot = gl ^ (vp&15)) — delivers identical (d,k) fragments.
__global__ __launch_bounds__(256, 2) void attn_kernel(
    const bf16* __restrict__ Q,   // [B,H,S,DK] (pre-scaled by key_scale*log2e)
    const bf16* __restrict__ K,   // [B,H,S,DK]
    const bf16* __restrict__ Vt,  // [B,H,DK,S]
    const float* __restrict__ mask,   // [B,S,S] fp32 (direct)
    const float* __restrict__ hscale, // [NH]
    bf16* __restrict__ O) {           // [B,S,H,DK]
  __shared__ bf16 Kl[2][32 * 128];  // 2 x 8 KB: 32 rows of 256B, slot = col16 ^ (row&15)
  __shared__ bf16 Vl[2][32 * 128];  // 2 x 8 KB: 32 quad-d rows of 256B, slot = gl ^ (vp&15)

  const int tid = threadIdx.x;
  const int lane = tid & 63;
  const int wv = tid >> 6;
  const int l31 = lane & 31;
  const int hi = lane >> 5;
  const int ksw16 = (l31 & 15) << 4;

  const int bid = blockIdx.x;
  const int xcd = bid & 7;
  const int slot_ = bid >> 3;
  const int g = xcd + ((slot_ >> 4) << 3);
  const int h = slot_ & 15;
  const int qt = g & 15;
  const int b = g >> 4;
  const int q0 = qt * 128;

  const float hs2 = hscale[h] * 1.44269504f;
  const float M0 = 8.0f;   // folded into the QK accumulator init

  const size_t bh = (size_t)(b * NH + h);
  const bf16* Qb = Q + bh * SEQ * DK;
  const bf16* Kb = K + bh * SEQ * DK;
  const bf16* Vb = Vt + bh * (size_t)DK * SEQ;
  const float* Mrow = mask + (size_t)b * SEQ * SEQ + (size_t)(q0 + wv * 32 + l31) * SEQ;

  bf16x8 qreg[8];
  {
    const bf16* qrow = Qb + (size_t)(q0 + wv * 32 + l31) * DK + hi * 8;
#pragma unroll
    for (int s = 0; s < 8; ++s) qreg[s] = *(const bf16x8*)(qrow + s * 16);
  }

  f32x16 acco[4];
#pragma unroll
  for (int nd = 0; nd < 4; ++nd) acco[nd] = (f32x16)(0.0f);
  float l_ = 0.f;

  const int st_sub = lane >> 4;            // 0..3
  const int st_gl0 = lane & 15;            // pre-XOR granule

  // ---- prologue: stage tile 0 (K and V), 8 chunks each over 4 waves (2/wave)
#pragma unroll
  for (int i = 0; i < 2; ++i) {
    const int chunk = wv * 2 + i;           // 0..7
    {
      const int r = chunk * 4 + st_sub;     // 0..31
      const int gl = st_gl0 ^ (r & 15);
      gload_lds16(Kb + (size_t)r * DK + gl * 8, Kl[0] + chunk * 512);
    }
    {
      const int vp = chunk * 4 + st_sub;    // 0..31
      const int gl = st_gl0 ^ (vp & 15);
      const int d = 4 * vp + (gl >> 2);
      gload_lds16(Vb + (size_t)d * SEQ + (gl & 3) * 8, Vl[0] + chunk * 512);
    }
  }
  __syncthreads();

  for (int t = 0; t < NT2; ++t) {
    const int kb0 = t * 32;
    const int cur = t & 1, nxt = cur ^ 1;
    const bf16* Kc = Kl[cur];
    const bf16* Vc = Vl[cur];

    // mask register loads for this tile (fp32 direct, float4 = 16B each)
    f32x4 mk[4];
#pragma unroll
    for (int c = 0; c < 4; ++c)
      mk[c] = *(const f32x4*)(Mrow + kb0 + c * 8 + hi * 4);

    // stage tile t+1
    if (t + 1 < NT2) {
#pragma unroll
      for (int i = 0; i < 2; ++i) {
        const int chunk = wv * 2 + i;
        {
          const int r = chunk * 4 + st_sub;
          const int gl = st_gl0 ^ (r & 15);
          gload_lds16(Kb + (size_t)(kb0 + 32 + r) * DK + gl * 8, Kl[nxt] + chunk * 512);
        }
        {
          const int vp = chunk * 4 + st_sub;
          const int gl = st_gl0 ^ (vp & 15);
          const int d = 4 * vp + (gl >> 2);
          gload_lds16(Vb + (size_t)d * SEQ + kb0 + 32 + (gl & 3) * 8, Vl[nxt] + chunk * 512);
        }
      }
    }

    // QK^T in log2 domain (Q pre-scaled); accumulator starts at -M0
    f32x16 p = (f32x16)(-M0);
    __builtin_amdgcn_s_setprio(1);
#pragma unroll
    for (int s = 0; s < 8; ++s) {
      const int byteoff = (s * 32 + hi * 16) ^ ksw16;
      bf16x8 k0 = *(const bf16x8*)((const char*)Kc + (size_t)l31 * 256 + byteoff);
      p = mfma32(k0, qreg[s], p);
    }
    __builtin_amdgcn_s_setprio(0);

    // P = exp2(p + mask*hs2)  — single FMA + exp2 per element
    float lg[16];
#pragma unroll
    for (int r = 0; r < 16; ++r)
      lg[r] = exp2_fast(p[r] + mk[r >> 2][r & 3] * hs2);

    // pack P -> PV A-frags via permlane32_swap (ks = 0,1)
    bf16x8 pa[2];
#pragma unroll
    for (int ks = 0; ks < 2; ++ks) {
      const int bo = ks * 8;
      const uint32_t w0 = cvtpk(lg[bo + 0], lg[bo + 1]);
      const uint32_t w1 = cvtpk(lg[bo + 2], lg[bo + 3]);
      const uint32_t w2 = cvtpk(lg[bo + 4], lg[bo + 5]);
      const uint32_t w3 = cvtpk(lg[bo + 6], lg[bo + 7]);
      uint2v s02 = __builtin_amdgcn_permlane32_swap(w0, w2, false, false);
      uint2v s13 = __builtin_amdgcn_permlane32_swap(w1, w3, false, false);
      union { uint32_t u[4]; bf16x8 v; } pk;
      pk.u[0] = s02[0];
      pk.u[1] = s13[0];
      pk.u[2] = s02[1];
      pk.u[3] = s13[1];
      pa[ks] = pk.v;
    }

    // PV: O[q][d] += P V ; V quad-d rows vp = nd*8 + (l31>>2)
    __builtin_amdgcn_s_setprio(1);
#pragma unroll
    for (int nd = 0; nd < 4; ++nd) {
      const int vpr = nd * 8 + (l31 >> 2);
      const int vrow = vpr * 256;
#pragma unroll
      for (int ks = 0; ks < 2; ++ks) {
        const int gl = (l31 & 3) * 4 + ks * 2 + hi;
        const int slot = gl ^ (vpr & 15);
        bf16x8 vf = *(const bf16x8*)((const char*)Vc + vrow + slot * 16);
        acco[nd] = mfma32(pa[ks], vf, acco[nd]);
      }
    }
    __builtin_amdgcn_s_setprio(0);

    // row-sum tree (feeds only the epilogue)
    float ts[8];
#pragma unroll
    for (int i = 0; i < 8; ++i) ts[i] = lg[i] + lg[i + 8];
#pragma unroll
    for (int i = 0; i < 4; ++i) ts[i] = ts[i] + ts[i + 4];
    float es = (ts[0] + ts[1]) + (ts[2] + ts[3]);
    es += __shfl_xor(es, 32);
    l_ += es;

    asm volatile("s_waitcnt vmcnt(0) lgkmcnt(0)" ::: "memory");
    __builtin_amdgcn_sched_barrier(0);
    __builtin_amdgcn_s_barrier();
  }

  const float inv = 1.f / l_;
#pragma unroll
  for (int r = 0; r < 16; ++r) {
    const int qloc = (r & 3) + 8 * (r >> 2) + 4 * hi;
    const float ivr = __shfl(inv, qloc);
    const int q_abs = q0 + wv * 32 + qloc;
    bf16* orow = O + (((size_t)(b * SEQ + q_abs) * NH + h) << 7) + l31;
#pragma unroll
    for (int nd = 0; nd < 4; ++nd) orow[nd * 32] = (bf16)(acco[nd][r] * ivr);
  }
}

extern "C" void kernel_launch(void* const* d_in, const int* in_sizes, int n_in,
                              void* d_out, int out_size, void* d_ws, size_t ws_size,
                              hipStream_t stream) {
  const float* states = (const float*)d_in[0];
  const float* maskp  = (const float*)d_in[1];
  const float* hscale = (const float*)d_in[2];
  const float* qw = (const float*)d_in[3];
  const float* qb = (const float*)d_in[4];
  const float* kw = (const float*)d_in[5];
  const float* kb = (const float*)d_in[6];
  const float* vw = (const float*)d_in[7];
  const float* vb = (const float*)d_in[8];
  const float* ow = (const float*)d_in[9];
  const float* ob = (const float*)d_in[10];

  char* ws = (char*)d_ws;
  const size_t SZ_ACT = (size_t)MTOT * DM * 2;  // 16 MiB
  const size_t SZ_W   = (size_t)DM * DM * 2;    // 8 MiB
  bf16* sb    = (bf16*)(ws);                    // states bf16; later reused as O buffer
  bf16* qbuf  = (bf16*)(ws + SZ_ACT);
  bf16* kbuf  = (bf16*)(ws + 2 * SZ_ACT);
  bf16* vtbuf = (bf16*)(ws + 3 * SZ_ACT);
  bf16* wcat  = (bf16*)(ws + 4 * SZ_ACT);       // wq|wk|wv|wo contiguous (4 x SZ_W)
  bf16* wob   = (bf16*)(ws + 4 * SZ_ACT + 3 * SZ_W);

  const int nAct4 = MTOT * DM / 4;
  const int nW4   = DM * DM / 4;

  cast_all_kernel<<<(nAct4 + 4 * nW4) / 256, 256, 0, stream>>>(states, qw, kw, vw, ow, sb, wcat);

  qkv_gemm<<<dim3(3 * DM / 128, MTOT / 128), dim3(256), 0, stream>>>(
      sb, wcat, qb, kb, vb, qbuf, kbuf, vtbuf);

  attn_kernel<<<dim3(NB * NH * (SEQ / 128)), dim3(256), 0, stream>>>(
      qbuf, kbuf, vtbuf, maskp, hscale, sb);

  gemm_oproj<<<dim3(DM / 128, MTOT / 128), dim3(256), 0, stream>>>(sb, wob, ob, (float*)d_out);
}

// Round 19
// 259.267 us; speedup vs baseline: 1.0216x; 1.0216x over previous
//
#include <hip/hip_runtime.h>
#include <hip/hip_bf16.h>
#include <stdint.h>

#define DM   2048
#define SEQ  2048
#define NB   2
#define NH   16
#define DK   128
#define MTOT (NB * SEQ) // 4096
#define NT   (SEQ / 64) // 32 k-tiles

typedef __bf16 bf16;
typedef __bf16 bf16x8 __attribute__((ext_vector_type(8)));
typedef __bf16 bf16x4v __attribute__((ext_vector_type(4)));
typedef float f32x4 __attribute__((ext_vector_type(4)));
typedef float f32x16 __attribute__((ext_vector_type(16)));
typedef unsigned uint2v __attribute__((ext_vector_type(2)));

__device__ __forceinline__ void gload_lds16(const void* g, void* l) {
  __builtin_amdgcn_global_load_lds((__attribute__((address_space(1))) void*)(g),
                                   (__attribute__((address_space(3))) void*)(l),
                                   16, 0, 0);
}

__device__ __forceinline__ f32x4 mfma16(bf16x8 a, bf16x8 b, f32x4 c) {
  return __builtin_amdgcn_mfma_f32_16x16x32_bf16(a, b, c, 0, 0, 0);
}
__device__ __forceinline__ f32x16 mfma32(bf16x8 a, bf16x8 b, f32x16 c) {
  return __builtin_amdgcn_mfma_f32_32x32x16_bf16(a, b, c, 0, 0, 0);
}
__device__ __forceinline__ uint32_t cvtpk(float lo, float hi) {
  uint32_t r;
  asm("v_cvt_pk_bf16_f32 %0, %1, %2" : "=v"(r) : "v"(lo), "v"(hi));
  return r;
}
__device__ __forceinline__ float exp2_fast(float x) {
  float r;
  asm("v_exp_f32 %0, %1" : "=v"(r) : "v"(x));
  return r;
}

// ---------------- fused fp32 -> bf16 cast: states + 4 weights, one launch ----------------
__global__ void cast_all_kernel(const float* __restrict__ s,
                                const float* __restrict__ w0, const float* __restrict__ w1,
                                const float* __restrict__ w2, const float* __restrict__ w3,
                                bf16* __restrict__ sb, bf16* __restrict__ wb) {
  const int i = blockIdx.x * blockDim.x + threadIdx.x;
  const int nAct4 = MTOT * DM / 4;
  const int nW4 = DM * DM / 4;
  const float* src;
  bf16* dst;
  int idx;
  if (i < nAct4) {
    src = s; dst = sb; idx = i;
  } else {
    const int j = i - nAct4;
    const int seg = j >> 20;                 // nW4 == 2^20
    src = (seg == 0) ? w0 : (seg == 1) ? w1 : (seg == 2) ? w2 : w3;
    dst = wb + ((size_t)seg << 20) * 4;
    idx = j & (nW4 - 1);
  }
  float4 v = reinterpret_cast<const float4*>(src)[idx];
  bf16x4v o;
  o[0] = (bf16)v.x; o[1] = (bf16)v.y; o[2] = (bf16)v.z; o[3] = (bf16)v.w;
  *reinterpret_cast<bf16x4v*>(dst + (size_t)idx * 4) = o;
}

// ---------------- merged QKV GEMM (128x128 tile, 4 waves — proven 2-D grid) ----------------
// Q output is pre-scaled by key_scale*log2(e) so attn's logit math is a single FMA.
__global__ __launch_bounds__(256, 2) void qkv_gemm(
    const bf16* __restrict__ A, const bf16* __restrict__ Wcat,
    const float* __restrict__ qb, const float* __restrict__ kb, const float* __restrict__ vb,
    bf16* __restrict__ qo, bf16* __restrict__ ko, bf16* __restrict__ vo) {
  __shared__ bf16 lA[128 * 64];
  __shared__ bf16 lB[128 * 64];

  const int tid = threadIdx.x;
  const int lane = tid & 63;
  const int wid = tid >> 6;
  const int wr = wid >> 1, wc = wid & 1;
  const int row0 = blockIdx.y * 128;
  const int col0 = blockIdx.x * 128;
  const int third = col0 >> 11;              // 0=q, 1=k, 2=v
  const float* bias = (third == 0) ? qb : (third == 1) ? kb : vb;
  const float osc = (third == 0) ? 0.12751740f : 1.0f;  // key_scale * log2(e) folded into Q

  const int srow = lane >> 3;
  const int scol = ((lane & 7) ^ srow) * 8;

  const int fr = lane & 15;
  const int fg = lane >> 4;

  f32x4 acc[4][4];
#pragma unroll
  for (int m = 0; m < 4; ++m)
#pragma unroll
    for (int n = 0; n < 4; ++n) { f32x4 z = {0.f, 0.f, 0.f, 0.f}; acc[m][n] = z; }

  for (int kt = 0; kt < DM / 64; ++kt) {
    const int k0 = kt * 64;
    __syncthreads();
#pragma unroll
    for (int i = 0; i < 4; ++i) {
      const int chunk = wid * 4 + i;
      const int r = chunk * 8 + srow;
      gload_lds16(A + (size_t)(row0 + r) * DM + k0 + scol, lA + chunk * 512);
      gload_lds16(Wcat + (size_t)(col0 + r) * DM + k0 + scol, lB + chunk * 512);
    }
    __syncthreads();
#pragma unroll
    for (int kk = 0; kk < 2; ++kk) {
      bf16x8 af[4], bw[4];
#pragma unroll
      for (int m = 0; m < 4; ++m) {
        const int r = wr * 64 + m * 16 + fr;
        const int cb = (kk * 64 + fg * 16) ^ ((r & 7) << 4);
        af[m] = *(const bf16x8*)((const char*)lA + r * 128 + cb);
      }
#pragma unroll
      for (int n = 0; n < 4; ++n) {
        const int r = wc * 64 + n * 16 + fr;
        const int cb = (kk * 64 + fg * 16) ^ ((r & 7) << 4);
        bw[n] = *(const bf16x8*)((const char*)lB + r * 128 + cb);
      }
#pragma unroll
      for (int m = 0; m < 4; ++m)
#pragma unroll
        for (int n = 0; n < 4; ++n) acc[m][n] = mfma16(af[m], bw[n], acc[m][n]);
    }
  }

#pragma unroll
  for (int m = 0; m < 4; ++m) {
#pragma unroll
    for (int n = 0; n < 4; ++n) {
      const int colg = col0 + wc * 64 + n * 16 + fr;
      const int col = colg & 2047;           // within third
      const float bs = bias[col];
      const int rbase = row0 + wr * 64 + m * 16 + fg * 4;
      const int h = col >> 7, d = col & 127;
      if (third < 2) {
        bf16* o = (third == 0) ? qo : ko;
#pragma unroll
        for (int r = 0; r < 4; ++r) {
          const int row = rbase + r;
          const int b = row >> 11, s = row & 2047;
          o[(((size_t)(b * NH + h) * SEQ + s) << 7) + d] = (bf16)((acc[m][n][r] + bs) * osc);
        }
      } else {
        const int b = rbase >> 11, s = rbase & 2047;
        bf16x4v pk;
#pragma unroll
        for (int r = 0; r < 4; ++r) pk[r] = (bf16)(acc[m][n][r] + bs);
        *reinterpret_cast<bf16x4v*>(vo + ((size_t)((b * NH + h) * DK + d) * SEQ + s)) = pk;
      }
    }
  }
}

// ---------------- O-projection GEMM (128x128, f32 out — proven 2-D grid) ----------------
__global__ __launch_bounds__(256, 2) void gemm_oproj(
    const bf16* __restrict__ A, const bf16* __restrict__ W,
    const float* __restrict__ bias, float* __restrict__ out) {
  __shared__ bf16 lA[128 * 64];
  __shared__ bf16 lB[128 * 64];

  const int tid = threadIdx.x;
  const int lane = tid & 63;
  const int wid = tid >> 6;
  const int wr = wid >> 1, wc = wid & 1;
  const int row0 = blockIdx.y * 128;
  const int col0 = blockIdx.x * 128;

  const int srow = lane >> 3;
  const int scol = ((lane & 7) ^ srow) * 8;

  const int fr = lane & 15;
  const int fg = lane >> 4;

  f32x4 acc[4][4];
#pragma unroll
  for (int m = 0; m < 4; ++m)
#pragma unroll
    for (int n = 0; n < 4; ++n) { f32x4 z = {0.f, 0.f, 0.f, 0.f}; acc[m][n] = z; }

  for (int kt = 0; kt < DM / 64; ++kt) {
    const int k0 = kt * 64;
    __syncthreads();
#pragma unroll
    for (int i = 0; i < 4; ++i) {
      const int chunk = wid * 4 + i;
      const int r = chunk * 8 + srow;
      gload_lds16(A + (size_t)(row0 + r) * DM + k0 + scol, lA + chunk * 512);
      gload_lds16(W + (size_t)(col0 + r) * DM + k0 + scol, lB + chunk * 512);
    }
    __syncthreads();
#pragma unroll
    for (int kk = 0; kk < 2; ++kk) {
      bf16x8 af[4], bw[4];
#pragma unroll
      for (int m = 0; m < 4; ++m) {
        const int r = wr * 64 + m * 16 + fr;
        const int cb = (kk * 64 + fg * 16) ^ ((r & 7) << 4);
        af[m] = *(const bf16x8*)((const char*)lA + r * 128 + cb);
      }
#pragma unroll
      for (int n = 0; n < 4; ++n) {
        const int r = wc * 64 + n * 16 + fr;
        const int cb = (kk * 64 + fg * 16) ^ ((r & 7) << 4);
        bw[n] = *(const bf16x8*)((const char*)lB + r * 128 + cb);
      }
#pragma unroll
      for (int m = 0; m < 4; ++m)
#pragma unroll
        for (int n = 0; n < 4; ++n) acc[m][n] = mfma16(af[m], bw[n], acc[m][n]);
    }
  }

#pragma unroll
  for (int m = 0; m < 4; ++m) {
#pragma unroll
    for (int n = 0; n < 4; ++n) {
      const int col = col0 + wc * 64 + n * 16 + fr;
      const float bs = bias[col];
      const int rbase = row0 + wr * 64 + m * 16 + fg * 4;
#pragma unroll
      for (int r = 0; r < 4; ++r) {
        const int row = rbase + r;
        out[(size_t)row * DM + col] = acc[m][n][r] + bs;
      }
    }
  }
}

// ---------------- flash attention: verified best (4 waves x 32 q-rows, KVBLK=64) ----------------
// Swapped QK^T, fixed-ref softmax (M0 in accumulator init), permlane pack,
// row-sum tree after the PV cluster.
__global__ __launch_bounds__(256, 2) void attn_kernel(
    const bf16* __restrict__ Q,   // [B,H,S,DK] (pre-scaled by key_scale*log2e)
    const bf16* __restrict__ K,   // [B,H,S,DK]
    const bf16* __restrict__ Vt,  // [B,H,DK,S]
    const float* __restrict__ mask,   // [B,S,S] fp32 (direct)
    const float* __restrict__ hscale, // [NH]
    bf16* __restrict__ O) {           // [B,S,H,DK]
  __shared__ bf16 Kl[2][64 * 128];  // 256B rows, granule slot = col16 ^ (row&15)
  __shared__ bf16 Vl[2][64 * 128];  // pair-rows (vp=d>>1) of 256B, slot = gl ^ (vp&15)

  const int tid = threadIdx.x;
  const int lane = tid & 63;
  const int wv = tid >> 6;
  const int l31 = lane & 31;
  const int hi = lane >> 5;
  const int ksw16 = (l31 & 15) << 4;
  const int vpbase = l31 >> 1;
  const int pvg = (l31 & 1) * 8 + hi;

  const int bid = blockIdx.x;
  const int xcd = bid & 7;
  const int slot_ = bid >> 3;
  const int g = xcd + ((slot_ >> 4) << 3);
  const int h = slot_ & 15;
  const int qt = g & 15;
  const int b = g >> 4;
  const int q0 = qt * 128;

  const float hs2 = hscale[h] * 1.44269504f;
  const float M0 = 8.0f;   // folded into the QK accumulator init below

  const size_t bh = (size_t)(b * NH + h);
  const bf16* Qb = Q + bh * SEQ * DK;
  const bf16* Kb = K + bh * SEQ * DK;
  const bf16* Vb = Vt + bh * (size_t)DK * SEQ;
  const float* Mrow = mask + (size_t)b * SEQ * SEQ + (size_t)(q0 + wv * 32 + l31) * SEQ;

  bf16x8 qreg[8];
  {
    const bf16* qrow = Qb + (size_t)(q0 + wv * 32 + l31) * DK + hi * 8;
#pragma unroll
    for (int s = 0; s < 8; ++s) qreg[s] = *(const bf16x8*)(qrow + s * 16);
  }

  f32x16 acco[4];
#pragma unroll
  for (int nd = 0; nd < 4; ++nd) acco[nd] = (f32x16)(0.0f);
  float l_ = 0.f;

  const int st_sub = lane >> 4;
  const int st_gl0 = lane & 15;

#pragma unroll
  for (int i = 0; i < 4; ++i) {
    const int chunk = wv * 4 + i;
    {
      const int r = chunk * 4 + st_sub;
      const int gl = st_gl0 ^ (r & 15);
      gload_lds16(Kb + (size_t)r * DK + gl * 8, Kl[0] + chunk * 512);
    }
    {
      const int vp = chunk * 4 + st_sub;
      const int gl = st_gl0 ^ (vp & 15);
      const int d = 2 * vp + (gl >> 3);
      gload_lds16(Vb + (size_t)d * SEQ + (gl & 7) * 8, Vl[0] + chunk * 512);
    }
  }
  __syncthreads();

  for (int t = 0; t < NT; ++t) {
    const int kb0 = t * 64;
    const int cur = t & 1, nxt = cur ^ 1;
    const bf16* Kc = Kl[cur];
    const bf16* Vc = Vl[cur];

    // mask register loads for this tile (fp32 direct, float4 = 16B each)
    f32x4 mk[2][4];
#pragma unroll
    for (int st = 0; st < 2; ++st)
#pragma unroll
      for (int c = 0; c < 4; ++c)
        mk[st][c] = *(const f32x4*)(Mrow + kb0 + st * 32 + c * 8 + hi * 4);

    if (t + 1 < NT) {
#pragma unroll
      for (int i = 0; i < 4; ++i) {
        const int chunk = wv * 4 + i;
        {
          const int r = chunk * 4 + st_sub;
          const int gl = st_gl0 ^ (r & 15);
          gload_lds16(Kb + (size_t)(kb0 + 64 + r) * DK + gl * 8, Kl[nxt] + chunk * 512);
        }
        {
          const int vp = chunk * 4 + st_sub;
          const int gl = st_gl0 ^ (vp & 15);
          const int d = 2 * vp + (gl >> 3);
          gload_lds16(Vb + (size_t)d * SEQ + kb0 + 64 + (gl & 7) * 8, Vl[nxt] + chunk * 512);
        }
      }
    }

    // QK^T in log2 domain (Q pre-scaled); accumulator starts at -M0
    f32x16 p[2];
#pragma unroll
    for (int st = 0; st < 2; ++st) p[st] = (f32x16)(-M0);
    __builtin_amdgcn_s_setprio(1);
#pragma unroll
    for (int s = 0; s < 8; ++s) {
      const int byteoff = (s * 32 + hi * 16) ^ ksw16;
      bf16x8 k0 = *(const bf16x8*)((const char*)Kc + (size_t)l31 * 256 + byteoff);
      bf16x8 k1 = *(const bf16x8*)((const char*)Kc + (size_t)(32 + l31) * 256 + byteoff);
      p[0] = mfma32(k0, qreg[s], p[0]);
      p[1] = mfma32(k1, qreg[s], p[1]);
    }
    __builtin_amdgcn_s_setprio(0);

    // P = exp2(p + mask*hs2)  — single FMA + exp2 per element
    float lg[32];
#pragma unroll
    for (int st = 0; st < 2; ++st)
#pragma unroll
      for (int r = 0; r < 16; ++r)
        lg[st * 16 + r] = exp2_fast(p[st][r] + mk[st][r >> 2][r & 3] * hs2);

    // pack P -> PV A-frags via permlane32_swap (one swap fills two words)
    bf16x8 pa[4];
#pragma unroll
    for (int ks = 0; ks < 4; ++ks) {
      const int bo = (ks & 1) * 8 + ((ks >> 1) << 4);
      const uint32_t w0 = cvtpk(lg[bo + 0], lg[bo + 1]);
      const uint32_t w1 = cvtpk(lg[bo + 2], lg[bo + 3]);
      const uint32_t w2 = cvtpk(lg[bo + 4], lg[bo + 5]);
      const uint32_t w3 = cvtpk(lg[bo + 6], lg[bo + 7]);
      uint2v s02 = __builtin_amdgcn_permlane32_swap(w0, w2, false, false);
      uint2v s13 = __builtin_amdgcn_permlane32_swap(w1, w3, false, false);
      union { uint32_t u[4]; bf16x8 v; } pk;
      pk.u[0] = s02[0];
      pk.u[1] = s13[0];
      pk.u[2] = s02[1];
      pk.u[3] = s13[1];
      pa[ks] = pk.v;
    }

    __builtin_amdgcn_s_setprio(1);
#pragma unroll
    for (int nd = 0; nd < 4; ++nd) {
      const int vrow = (nd * 16 + vpbase) * 256;
#pragma unroll
      for (int ks = 0; ks < 4; ++ks) {
        const int slot = (pvg + ks * 2) ^ vpbase;
        bf16x8 vf = *(const bf16x8*)((const char*)Vc + vrow + slot * 16);
        acco[nd] = mfma32(pa[ks], vf, acco[nd]);
      }
    }
    __builtin_amdgcn_s_setprio(0);

    // row-sum tree AFTER PV (only feeds the epilogue; overlaps MFMA drain)
    float ts[16];
#pragma unroll
    for (int i = 0; i < 16; ++i) ts[i] = lg[i] + lg[i + 16];
#pragma unroll
    for (int i = 0; i < 8; ++i) ts[i] = ts[i] + ts[i + 8];
#pragma unroll
    for (int i = 0; i < 4; ++i) ts[i] = ts[i] + ts[i + 4];
    float es = (ts[0] + ts[1]) + (ts[2] + ts[3]);
    es += __shfl_xor(es, 32);
    l_ += es;

    asm volatile("s_waitcnt vmcnt(0) lgkmcnt(0)" ::: "memory");
    __builtin_amdgcn_sched_barrier(0);
    __builtin_amdgcn_s_barrier();
  }

  const float inv = 1.f / l_;
#pragma unroll
  for (int r = 0; r < 16; ++r) {
    const int qloc = (r & 3) + 8 * (r >> 2) + 4 * hi;
    const float ivr = __shfl(inv, qloc);
    const int q_abs = q0 + wv * 32 + qloc;
    bf16* orow = O + (((size_t)(b * SEQ + q_abs) * NH + h) << 7) + l31;
#pragma unroll
    for (int nd = 0; nd < 4; ++nd) orow[nd * 32] = (bf16)(acco[nd][r] * ivr);
  }
}

extern "C" void kernel_launch(void* const* d_in, const int* in_sizes, int n_in,
                              void* d_out, int out_size, void* d_ws, size_t ws_size,
                              hipStream_t stream) {
  const float* states = (const float*)d_in[0];
  const float* maskp  = (const float*)d_in[1];
  const float* hscale = (const float*)d_in[2];
  const float* qw = (const float*)d_in[3];
  const float* qb = (const float*)d_in[4];
  const float* kw = (const float*)d_in[5];
  const float* kb = (const float*)d_in[6];
  const float* vw = (const float*)d_in[7];
  const float* vb = (const float*)d_in[8];
  const float* ow = (const float*)d_in[9];
  const float* ob = (const float*)d_in[10];

  char* ws = (char*)d_ws;
  const size_t SZ_ACT = (size_t)MTOT * DM * 2;  // 16 MiB
  const size_t SZ_W   = (size_t)DM * DM * 2;    // 8 MiB
  bf16* sb    = (bf16*)(ws);                    // states bf16; later reused as O buffer
  bf16* qbuf  = (bf16*)(ws + SZ_ACT);
  bf16* kbuf  = (bf16*)(ws + 2 * SZ_ACT);
  bf16* vtbuf = (bf16*)(ws + 3 * SZ_ACT);
  bf16* wcat  = (bf16*)(ws + 4 * SZ_ACT);       // wq|wk|wv|wo contiguous (4 x SZ_W)
  bf16* wob   = (bf16*)(ws + 4 * SZ_ACT + 3 * SZ_W);

  const int nAct4 = MTOT * DM / 4;
  const int nW4   = DM * DM / 4;

  cast_all_kernel<<<(nAct4 + 4 * nW4) / 256, 256, 0, stream>>>(states, qw, kw, vw, ow, sb, wcat);

  qkv_gemm<<<dim3(3 * DM / 128, MTOT / 128), dim3(256), 0, stream>>>(
      sb, wcat, qb, kb, vb, qbuf, kbuf, vtbuf);

  attn_kernel<<<dim3(NB * NH * (SEQ / 128)), dim3(256), 0, stream>>>(
      qbuf, kbuf, vtbuf, maskp, hscale, sb);

  gemm_oproj<<<dim3(DM / 128, MTOT / 128), dim3(256), 0, stream>>>(sb, wob, ob, (float*)d_out);
}